// Round 5
// baseline (237.682 us; speedup 1.0000x reference)
//
#include <hip/hip_runtime.h>

typedef __attribute__((ext_vector_type(8))) short short8;
typedef __attribute__((ext_vector_type(4))) float f32x4;
typedef __attribute__((ext_vector_type(16))) float f32x16;
typedef __attribute__((ext_vector_type(4))) int i32x4;

__device__ __forceinline__ unsigned short f2bf(float f){
  union { float f; unsigned int u; } cv; cv.f = f;
  unsigned int u = cv.u;
  u = (u + 0x7fffu + ((u >> 16) & 1u)) >> 16;
  return (unsigned short)u;
}
__device__ __forceinline__ float bf2f(unsigned short h){
  union { unsigned int u; float f; } cv; cv.u = ((unsigned int)h) << 16;
  return cv.f;
}

typedef unsigned int u32g __attribute__((address_space(1)));
typedef unsigned int u32l __attribute__((address_space(3)));
__device__ __forceinline__ void gload16(const void* g, void* l){
  __builtin_amdgcn_global_load_lds((const u32g*)g, (u32l*)l, 16, 0, 0);
}

__device__ __forceinline__ unsigned int cvtpk_bf16(float lo, float hi){
  unsigned int r;
  asm("v_cvt_pk_bf16_f32 %0, %1, %2" : "=v"(r) : "v"(lo), "v"(hi));
  return r;
}

#define BARRIER() asm volatile("s_barrier" ::: "memory")
#define WAITV0()  asm volatile("s_waitcnt vmcnt(0)" ::: "memory")

// ---------------- reduction: per-batch mean / rstd ----------------
__global__ __launch_bounds__(256) void reduce_partial_k(const float* __restrict__ x,
                                                        float2* __restrict__ partial){
  const int b = blockIdx.y, blk = blockIdx.x;
  const float4* xp = (const float4*)(x + (size_t)b*1048576 + (size_t)blk*16384);
  float s = 0.f, sq = 0.f;
  #pragma unroll
  for (int i = 0; i < 16; ++i){
    float4 v = xp[threadIdx.x + i*256];
    s  += v.x + v.y + v.z + v.w;
    sq += v.x*v.x + v.y*v.y + v.z*v.z + v.w*v.w;
  }
  #pragma unroll
  for (int m = 1; m < 64; m <<= 1){ s += __shfl_xor(s, m); sq += __shfl_xor(sq, m); }
  __shared__ float2 acc[4];
  if ((threadIdx.x & 63) == 0) acc[threadIdx.x >> 6] = make_float2(s, sq);
  __syncthreads();
  if (threadIdx.x == 0){
    float S = 0.f, Q = 0.f;
    for (int i = 0; i < 4; ++i){ S += acc[i].x; Q += acc[i].y; }
    partial[b*64 + blk] = make_float2(S, Q);
  }
}

__global__ __launch_bounds__(256) void reduce_final_k(const float2* __restrict__ partial,
                                                      float2* __restrict__ stats){
  const int w = threadIdx.x >> 6, lane = threadIdx.x & 63;
  float2 p = partial[w*64 + lane];
  float s = p.x, q = p.y;
  #pragma unroll
  for (int m = 1; m < 64; m <<= 1){ s += __shfl_xor(s, m); q += __shfl_xor(q, m); }
  if (lane == 0){
    const float inv = 1.0f/1048576.0f;
    float mean = s*inv;
    float var  = q*inv - mean*mean;
    stats[w] = make_float2(mean, rsqrtf(var + 1e-6f));
  }
}

// ---------------- weight conversion (fold scale*log2e into Q) ----------------
__global__ __launch_bounds__(256) void convert_w_k(const float* __restrict__ qkv_w,
                                                   const float* __restrict__ qkv_b,
                                                   const float* __restrict__ proj_w,
                                                   unsigned short* __restrict__ Wqk,
                                                   unsigned short* __restrict__ Wv,
                                                   unsigned short* __restrict__ Wp,
                                                   float* __restrict__ bias_qk){
  const float SQ = 0.0625f * 1.44269504088896340736f; // (C^-0.5) * log2(e)
  int id = blockIdx.x * 256 + threadIdx.x;
  if (id < 131072){                       // q,k rows (o < 512)
    int o = id >> 8;
    float sc = (o < 256) ? SQ : 1.0f;
    Wqk[id] = f2bf(qkv_w[id] * sc);
    if (id < 512) bias_qk[id] = qkv_b[id] * ((id < 256) ? SQ : 1.0f);
  } else if (id < 196608){                // v rows (o in [512,768))
    Wv[id - 131072] = f2bf(qkv_w[id]);
  } else {                                // proj
    int j = id - 196608;
    Wp[j] = f2bf(proj_w[j]);
  }
}

// ---------------- GroupNorm + transpose: x[b][c][n] -> xn_t[b][n][c] bf16 ----------------
__global__ __launch_bounds__(256) void norm_transpose_k(const float* __restrict__ x,
                                                        const float* __restrict__ gamma,
                                                        const float* __restrict__ beta,
                                                        const float2* __restrict__ stats,
                                                        unsigned short* __restrict__ xnt){
  __shared__ float tile[64][65];
  const int b = blockIdx.z, n0 = blockIdx.x*64, c0 = blockIdx.y*64;
  const float2 st = stats[b];
  const int t = threadIdx.x;
  const int col = t & 63, rb = t >> 6;
  #pragma unroll
  for (int i = 0; i < 16; ++i){
    int rr = i*4 + rb;
    float xv = x[((size_t)b*256 + c0 + rr)*4096 + n0 + col];
    tile[rr][col] = (xv - st.x) * st.y * gamma[c0+rr] + beta[c0+rr];
  }
  __syncthreads();
  #pragma unroll
  for (int i = 0; i < 16; ++i){
    int nr = i*4 + rb;
    xnt[((size_t)b*4096 + n0 + nr)*256 + c0 + col] = f2bf(tile[col][nr]);
  }
}

// ---------------- NT GEMM: C[m][n] = sum_k A[m][k]*B[n][k], K=256 ----------------
__global__ __launch_bounds__(256) void gemm_nt_k(const unsigned short* __restrict__ A,
                                                 const unsigned short* __restrict__ B,
                                                 int lda, int ldb, long sA, long sB,
                                                 const float* __restrict__ bias_m,
                                                 const float* __restrict__ bias_n,
                                                 const float* __restrict__ resid, long sR,
                                                 float* __restrict__ outF,
                                                 unsigned short* __restrict__ outB,
                                                 int ldc, long sC){
  __shared__ unsigned short As[64][40];
  __shared__ unsigned short Bs[64][40];
  const int b  = blockIdx.z;
  const int m0 = blockIdx.x * 64, n0 = blockIdx.y * 64;
  const unsigned short* Ab = A + (size_t)b * sA;
  const unsigned short* Bb = B + (size_t)b * sB;
  const int t = threadIdx.x;
  const int lane = t & 63, w = t >> 6;
  const int g = lane >> 4, r = lane & 15;
  const int wm = (w >> 1) * 32, wn = (w & 1) * 32;
  const int lrow = t >> 2, lcol = (t & 3) * 8;
  f32x4 acc00 = {0,0,0,0}, acc01 = {0,0,0,0}, acc10 = {0,0,0,0}, acc11 = {0,0,0,0};
  for (int ks = 0; ks < 8; ++ks){
    short8 av = *(const short8*)(Ab + (size_t)(m0 + lrow) * lda + ks*32 + lcol);
    short8 bv = *(const short8*)(Bb + (size_t)(n0 + lrow) * ldb + ks*32 + lcol);
    __syncthreads();
    *(short8*)&As[lrow][lcol] = av;
    *(short8*)&Bs[lrow][lcol] = bv;
    __syncthreads();
    short8 af0 = *(const short8*)&As[wm + r][g*8];
    short8 af1 = *(const short8*)&As[wm + 16 + r][g*8];
    short8 bf0 = *(const short8*)&Bs[wn + r][g*8];
    short8 bf1 = *(const short8*)&Bs[wn + 16 + r][g*8];
    acc00 = __builtin_amdgcn_mfma_f32_16x16x32_bf16(af0, bf0, acc00, 0, 0, 0);
    acc01 = __builtin_amdgcn_mfma_f32_16x16x32_bf16(af0, bf1, acc01, 0, 0, 0);
    acc10 = __builtin_amdgcn_mfma_f32_16x16x32_bf16(af1, bf0, acc10, 0, 0, 0);
    acc11 = __builtin_amdgcn_mfma_f32_16x16x32_bf16(af1, bf1, acc11, 0, 0, 0);
  }
  f32x4 accs[2][2] = {{acc00, acc01},{acc10, acc11}};
  #pragma unroll
  for (int mi = 0; mi < 2; ++mi)
    #pragma unroll
    for (int ni = 0; ni < 2; ++ni)
      #pragma unroll
      for (int j = 0; j < 4; ++j){
        int gm = m0 + wm + mi*16 + g*4 + j;
        int gn = n0 + wn + ni*16 + r;
        float vv = accs[mi][ni][j];
        if (bias_m) vv += bias_m[gm];
        if (bias_n) vv += bias_n[gn];
        if (resid)  vv += resid[(size_t)b*sR + (size_t)gm*ldc + gn];
        size_t off = (size_t)b*sC + (size_t)gm*ldc + gn;
        if (outB) outB[off] = f2bf(vv); else outF[off] = vv;
      }
}

// ---------------- flash attention: 512 blocks (2/CU), 4 q-waves share one K/V tile ----------------
// q,k in qk[b][n][512] (q=c<256, k=c>=256), v in vbuf[b][c][n].
// Writes unnormalized partial O (bf16, [b][ks][c][q]) + m/l; merged by attn_merge_k.
__global__ __launch_bounds__(256, 2) void attn_k(const unsigned short* __restrict__ qk,
                                                 const unsigned short* __restrict__ vbuf,
                                                 unsigned short* __restrict__ po,
                                                 float* __restrict__ ml){
  __shared__ __align__(16) char smem[65536];  // [buf2][K 16KB | V 16KB]
  // XCD-aware remap: all 32 q-blocks of a (b,ks) combo land on 2 combos/XCD
  const int id = blockIdx.x;
  const int xcd = id & 7, j = id >> 3;
  const int combo = xcd + 8*(j >> 5);
  const int qb = j & 31;
  const int b = combo >> 2, ks = combo & 3;
  const int q0 = qb * 128;
  const int t = threadIdx.x, lane = t & 63, w = t >> 6;
  const int hi = lane >> 5, l31 = lane & 31;
  const unsigned short* qkb = qk + (size_t)b * 4096 * 512;
  const unsigned short* vb  = vbuf + (size_t)b * 256 * 4096;

  // staging: waves 0,1 -> K (16 rows each), waves 2,3 -> V (128 c-rows each)
  auto stage = [&](int kc, char* buf){
    if (w < 2){
      #pragma unroll
      for (int ii = 0; ii < 8; ++ii){
        int rr = w*16 + 2*ii + hi;
        const unsigned short* src = qkb + (size_t)(kc + rr)*512 + 256
                                  + (((l31*16) ^ ((rr & 15) << 4)) >> 1);
        gload16(src, buf + (w*16 + 2*ii)*512);
      }
    } else {
      #pragma unroll
      for (int ii = 0; ii < 8; ++ii){
        int c = (w-2)*128 + 16*ii + (lane >> 2);
        const unsigned short* src = vb + (size_t)c*4096 + kc
                                  + ((((lane & 3)*16) ^ (((lane >> 3) & 3) << 4)) >> 1);
        gload16(src, buf + 16384 + ((w-2)*128 + 16*ii)*64);
      }
    }
  };

  // Q fragments: wave owns q-rows q0 + w*32 + l31 (B-operand)
  short8 qf[16];
  {
    const unsigned short* qrow = qkb + (size_t)(q0 + w*32 + l31) * 512;
    #pragma unroll
    for (int s = 0; s < 16; ++s) qf[s] = *(const short8*)(qrow + s*16 + hi*8);
  }

  f32x16 O[8];
  #pragma unroll
  for (int cb = 0; cb < 8; ++cb)
    #pragma unroll
    for (int jj = 0; jj < 16; ++jj) O[cb][jj] = 0.f;
  float mref = -1e30f, lrun = 0.f;

  const int kswz = (l31 & 15) << 4;
  const int vswz = ((l31 >> 1) & 3) << 4;

  stage(ks*1024, smem);   // prologue: tile 0 -> buf 0

  for (int kt = 0; kt < 32; ++kt){
    char* cur = smem + (kt & 1)*32768;

    WAITV0();    // own tile-kt stages landed (issued a full iteration ago)
    BARRIER();   // all waves' tile-kt staged; prev buffer fully consumed

    if (kt < 31) stage(ks*1024 + (kt+1)*32, smem + ((kt+1) & 1)*32768);

    // ---- S^T = K·Q : 16 c-steps, 2 chains ----
    f32x16 Sa, Sb;
    #pragma unroll
    for (int jj = 0; jj < 16; ++jj){ Sa[jj] = 0.f; Sb[jj] = 0.f; }
    #pragma unroll
    for (int s = 0; s < 8; ++s){
      short8 k0 = *(const short8*)(cur + l31*512 + (((2*s  )*32 + hi*16) ^ kswz));
      short8 k1 = *(const short8*)(cur + l31*512 + (((2*s+1)*32 + hi*16) ^ kswz));
      Sa = __builtin_amdgcn_mfma_f32_32x32x16_bf16(k0, qf[2*s  ], Sa, 0, 0, 0);
      Sb = __builtin_amdgcn_mfma_f32_32x32x16_bf16(k1, qf[2*s+1], Sb, 0, 0, 0);
    }
    f32x16 S = Sa + Sb;

    // ---- online softmax over k (lane-local + cross-half), defer-max THR=8 ----
    float m01 = fmaxf(S[0], S[1]),   m23 = fmaxf(S[2], S[3]);
    float m45 = fmaxf(S[4], S[5]),   m67 = fmaxf(S[6], S[7]);
    float m89 = fmaxf(S[8], S[9]),   mab = fmaxf(S[10], S[11]);
    float mcd = fmaxf(S[12], S[13]), mef = fmaxf(S[14], S[15]);
    float mx = fmaxf(fmaxf(fmaxf(m01, m23), fmaxf(m45, m67)),
                     fmaxf(fmaxf(m89, mab), fmaxf(mcd, mef)));
    mx = fmaxf(mx, __shfl_xor(mx, 32));
    if (__any(mx > mref + 8.0f)){
      float mnew = fmaxf(mref, mx);
      float al = exp2f(mref - mnew);
      lrun *= al;
      #pragma unroll
      for (int cb = 0; cb < 8; ++cb)
        #pragma unroll
        for (int jj = 0; jj < 16; ++jj) O[cb][jj] *= al;
      mref = mnew;
    }
    float p[16];
    #pragma unroll
    for (int jj = 0; jj < 16; ++jj) p[jj] = exp2f(S[jj] - mref);
    lrun += ((p[0]+p[1]) + (p[2]+p[3])) + ((p[4]+p[5]) + (p[6]+p[7]))
          + ((p[8]+p[9]) + (p[10]+p[11])) + ((p[12]+p[13]) + (p[14]+p[15]));

    // ---- pack P -> bf16 B-fragments (in-register) ----
    unsigned int w0 = cvtpk_bf16(p[0],  p[1]),  w1 = cvtpk_bf16(p[2],  p[3]);
    unsigned int w2 = cvtpk_bf16(p[4],  p[5]),  w3 = cvtpk_bf16(p[6],  p[7]);
    unsigned int w4 = cvtpk_bf16(p[8],  p[9]),  w5 = cvtpk_bf16(p[10], p[11]);
    unsigned int w6 = cvtpk_bf16(p[12], p[13]), w7 = cvtpk_bf16(p[14], p[15]);
    asm("v_permlane32_swap_b32 %0, %1" : "+v"(w0), "+v"(w2));
    asm("v_permlane32_swap_b32 %0, %1" : "+v"(w1), "+v"(w3));
    asm("v_permlane32_swap_b32 %0, %1" : "+v"(w4), "+v"(w6));
    asm("v_permlane32_swap_b32 %0, %1" : "+v"(w5), "+v"(w7));
    i32x4 pw0 = {(int)w0, (int)w1, (int)w2, (int)w3};
    i32x4 pw1 = {(int)w4, (int)w5, (int)w6, (int)w7};
    short8 pa0 = __builtin_bit_cast(short8, pw0);
    short8 pa1 = __builtin_bit_cast(short8, pw1);

    // ---- O^T += V·P^T : 8 independent c-block chains ----
    const char* Vt = cur + 16384;
    #pragma unroll
    for (int cb = 0; cb < 8; ++cb){
      const char* vrow = Vt + (cb*32 + l31)*64;
      short8 vf0 = *(const short8*)(vrow + ((hi*16) ^ vswz));
      O[cb] = __builtin_amdgcn_mfma_f32_32x32x16_bf16(vf0, pa0, O[cb], 0, 0, 0);
      short8 vf1 = *(const short8*)(vrow + ((32 + hi*16) ^ vswz));
      O[cb] = __builtin_amdgcn_mfma_f32_32x32x16_bf16(vf1, pa1, O[cb], 0, 0, 0);
    }
  }

  // ---- epilogue: write unnormalized partials (coalesced along q) ----
  float lf = lrun + __shfl_xor(lrun, 32);
  const int qg = q0 + w*32 + l31;
  unsigned short* pob = po + (size_t)(b*4 + ks) * 1048576;   // [256 c][4096 q]
  #pragma unroll
  for (int cb = 0; cb < 8; ++cb)
    #pragma unroll
    for (int jj = 0; jj < 16; ++jj){
      int c = cb*32 + (jj & 3) + 8*(jj >> 2) + 4*hi;
      pob[(size_t)c*4096 + qg] = f2bf(O[cb][jj]);
    }
  if (lane < 32){
    float* mlb = ml + (size_t)(b*4 + ks) * 8192;
    mlb[qg] = mref;
    mlb[4096 + qg] = lf;
  }
}

// ---------------- merge the 4 k-chunks: out ho[b][q][c] bf16 ----------------
__global__ __launch_bounds__(256) void attn_merge_k(const unsigned short* __restrict__ po,
                                                    const float* __restrict__ ml,
                                                    unsigned short* __restrict__ ho){
  __shared__ float Of[64][261];
  const int b = blockIdx.y, q0 = blockIdx.x * 64;
  const int t = threadIdx.x, ql = t & 63, ci = t >> 6;
  const int q = q0 + ql;
  float m0 = ml[(size_t)(b*4+0)*8192 + q], m1 = ml[(size_t)(b*4+1)*8192 + q];
  float m2 = ml[(size_t)(b*4+2)*8192 + q], m3 = ml[(size_t)(b*4+3)*8192 + q];
  float M = fmaxf(fmaxf(m0, m1), fmaxf(m2, m3));
  float e0 = exp2f(m0 - M), e1 = exp2f(m1 - M), e2 = exp2f(m2 - M), e3 = exp2f(m3 - M);
  float L = ml[(size_t)(b*4+0)*8192 + 4096 + q]*e0 + ml[(size_t)(b*4+1)*8192 + 4096 + q]*e1
          + ml[(size_t)(b*4+2)*8192 + 4096 + q]*e2 + ml[(size_t)(b*4+3)*8192 + 4096 + q]*e3;
  float inv = 1.0f / L;
  float acc[64];
  #pragma unroll
  for (int i = 0; i < 64; ++i) acc[i] = 0.f;
  #pragma unroll
  for (int ksv = 0; ksv < 4; ++ksv){
    float ee = (ksv == 0) ? e0 : (ksv == 1) ? e1 : (ksv == 2) ? e2 : e3;
    const unsigned short* pb = po + (size_t)(b*4 + ksv)*1048576 + q;
    #pragma unroll
    for (int i = 0; i < 64; ++i)
      acc[i] += bf2f(pb[(size_t)(ci + 4*i)*4096]) * ee;
  }
  #pragma unroll
  for (int i = 0; i < 64; ++i) Of[ql][ci + 4*i] = acc[i] * inv;
  __syncthreads();
  const int qr = t >> 2, sub = t & 3;
  const float* rowp = Of[qr];
  unsigned short* dst = ho + ((size_t)(b*4096 + q0 + qr))*256;
  #pragma unroll
  for (int jj = 0; jj < 8; ++jj){
    int c = sub*8 + jj*32;
    float4 v0 = *(const float4*)(rowp + c);
    float4 v1 = *(const float4*)(rowp + c + 4);
    short8 o;
    o[0] = (short)f2bf(v0.x); o[1] = (short)f2bf(v0.y);
    o[2] = (short)f2bf(v0.z); o[3] = (short)f2bf(v0.w);
    o[4] = (short)f2bf(v1.x); o[5] = (short)f2bf(v1.y);
    o[6] = (short)f2bf(v1.z); o[7] = (short)f2bf(v1.w);
    *(short8*)(dst + c) = o;
  }
}

// ---------------- launch ----------------
extern "C" void kernel_launch(void* const* d_in, const int* in_sizes, int n_in,
                              void* d_out, int out_size, void* d_ws, size_t ws_size,
                              hipStream_t stream){
  const float* x      = (const float*)d_in[0];
  const float* gamma  = (const float*)d_in[1];
  const float* beta   = (const float*)d_in[2];
  const float* qkv_w  = (const float*)d_in[3];
  const float* qkv_b  = (const float*)d_in[4];
  const float* proj_w = (const float*)d_in[5];
  const float* proj_b = (const float*)d_in[6];
  float* out = (float*)d_out;
  char* ws = (char*)d_ws;

  float2* partial        = (float2*)(ws + 0);        // 2048 B
  float2* stats          = (float2*)(ws + 2048);     // 32 B
  float*  bias_qk        = (float*)(ws + 4096);      // 2048 B
  unsigned short* Wqk    = (unsigned short*)(ws + 8192);      // 512x256 bf16
  unsigned short* Wv     = (unsigned short*)(ws + 270336);    // 256x256
  unsigned short* Wp     = (unsigned short*)(ws + 401408);    // 256x256
  unsigned short* xnt    = (unsigned short*)(ws + 532480);    // 4x4096x256 bf16 (8.4 MB)
  unsigned short* qkbuf  = (unsigned short*)(ws + 8921088);   // 4x4096x512 bf16 (16.8 MB)
  unsigned short* vbuf   = (unsigned short*)(ws + 25698304);  // 4x256x4096 bf16 (8.4 MB)
  unsigned short* po     = (unsigned short*)(ws + 34086912);  // 16x256x4096 bf16 (33.6 MB)
  float*          ml     = (float*)(ws + 67641344);           // 16x2x4096 f32 (512 KB)
  unsigned short* ho     = xnt;  // xnt dead after QKV gemms -> reuse for attention output

  reduce_partial_k<<<dim3(64,4), 256, 0, stream>>>(x, partial);
  reduce_final_k<<<1, 256, 0, stream>>>(partial, stats);
  convert_w_k<<<1024, 256, 0, stream>>>(qkv_w, qkv_b, proj_w, Wqk, Wv, Wp, bias_qk);
  norm_transpose_k<<<dim3(64,4,4), 256, 0, stream>>>(x, gamma, beta, stats, xnt);
  // qk[b][n][o] = xn_t[b][n][:] . Wqk[o][:]   (M=4096, N=512)
  gemm_nt_k<<<dim3(64,8,4), 256, 0, stream>>>(xnt, Wqk, 256, 256, 4096L*256, 0,
      nullptr, bias_qk, nullptr, 0, nullptr, qkbuf, 512, 4096L*512);
  // v[b][o][n] = Wv[o][:] . xn_t[b][n][:]     (M=256, N=4096)
  gemm_nt_k<<<dim3(4,64,4), 256, 0, stream>>>(Wv, xnt, 256, 256, 0, 4096L*256,
      qkv_b + 512, nullptr, nullptr, 0, nullptr, vbuf, 4096, 256L*4096);
  attn_k<<<dim3(512), 256, 0, stream>>>(qkbuf, vbuf, po, ml);
  attn_merge_k<<<dim3(64,4), 256, 0, stream>>>(po, ml, ho);
  // out[b][o][n] = Wp[o][:] . ho[b][n][:] + proj_b[o] + x[b][o][n]
  gemm_nt_k<<<dim3(4,64,4), 256, 0, stream>>>(Wp, ho, 256, 256, 0, 4096L*256,
      proj_b, nullptr, x, 1048576L, out, nullptr, 4096, 1048576L);
}

// Round 6
// 155.663 us; speedup vs baseline: 1.5269x; 1.5269x over previous
//
#include <hip/hip_runtime.h>

typedef __attribute__((ext_vector_type(8))) short short8;
typedef __attribute__((ext_vector_type(4))) float f32x4;
typedef __attribute__((ext_vector_type(16))) float f32x16;
typedef __attribute__((ext_vector_type(4))) int i32x4;

__device__ __forceinline__ unsigned short f2bf(float f){
  union { float f; unsigned int u; } cv; cv.f = f;
  unsigned int u = cv.u;
  u = (u + 0x7fffu + ((u >> 16) & 1u)) >> 16;
  return (unsigned short)u;
}
__device__ __forceinline__ float bf2f(unsigned short h){
  union { unsigned int u; float f; } cv; cv.u = ((unsigned int)h) << 16;
  return cv.f;
}

typedef unsigned int u32g __attribute__((address_space(1)));
typedef unsigned int u32l __attribute__((address_space(3)));
__device__ __forceinline__ void gload16(const void* g, void* l){
  __builtin_amdgcn_global_load_lds((const u32g*)g, (u32l*)l, 16, 0, 0);
}

__device__ __forceinline__ unsigned int cvtpk_bf16(float lo, float hi){
  unsigned int r;
  asm("v_cvt_pk_bf16_f32 %0, %1, %2" : "=v"(r) : "v"(lo), "v"(hi));
  return r;
}

#define BARRIER() asm volatile("s_barrier" ::: "memory")
#define WAITV0()  asm volatile("s_waitcnt vmcnt(0)" ::: "memory")
#define WAITLGKM0() asm volatile("s_waitcnt lgkmcnt(0)" ::: "memory")

// ---------------- reduction: per-batch mean / rstd ----------------
__global__ __launch_bounds__(256) void reduce_partial_k(const float* __restrict__ x,
                                                        float2* __restrict__ partial){
  const int b = blockIdx.y, blk = blockIdx.x;
  const float4* xp = (const float4*)(x + (size_t)b*1048576 + (size_t)blk*16384);
  float s = 0.f, sq = 0.f;
  #pragma unroll
  for (int i = 0; i < 16; ++i){
    float4 v = xp[threadIdx.x + i*256];
    s  += v.x + v.y + v.z + v.w;
    sq += v.x*v.x + v.y*v.y + v.z*v.z + v.w*v.w;
  }
  #pragma unroll
  for (int m = 1; m < 64; m <<= 1){ s += __shfl_xor(s, m); sq += __shfl_xor(sq, m); }
  __shared__ float2 acc[4];
  if ((threadIdx.x & 63) == 0) acc[threadIdx.x >> 6] = make_float2(s, sq);
  __syncthreads();
  if (threadIdx.x == 0){
    float S = 0.f, Q = 0.f;
    for (int i = 0; i < 4; ++i){ S += acc[i].x; Q += acc[i].y; }
    partial[b*64 + blk] = make_float2(S, Q);
  }
}

__global__ __launch_bounds__(256) void reduce_final_k(const float2* __restrict__ partial,
                                                      float2* __restrict__ stats){
  const int w = threadIdx.x >> 6, lane = threadIdx.x & 63;
  float2 p = partial[w*64 + lane];
  float s = p.x, q = p.y;
  #pragma unroll
  for (int m = 1; m < 64; m <<= 1){ s += __shfl_xor(s, m); q += __shfl_xor(q, m); }
  if (lane == 0){
    const float inv = 1.0f/1048576.0f;
    float mean = s*inv;
    float var  = q*inv - mean*mean;
    stats[w] = make_float2(mean, rsqrtf(var + 1e-6f));
  }
}

// ---------------- weight conversion (fold scale*log2e into Q) ----------------
__global__ __launch_bounds__(256) void convert_w_k(const float* __restrict__ qkv_w,
                                                   const float* __restrict__ qkv_b,
                                                   const float* __restrict__ proj_w,
                                                   unsigned short* __restrict__ Wqk,
                                                   unsigned short* __restrict__ Wv,
                                                   unsigned short* __restrict__ Wp,
                                                   float* __restrict__ bias_qk){
  const float SQ = 0.0625f * 1.44269504088896340736f; // (C^-0.5) * log2(e)
  int id = blockIdx.x * 256 + threadIdx.x;
  if (id < 131072){                       // q,k rows (o < 512)
    int o = id >> 8;
    float sc = (o < 256) ? SQ : 1.0f;
    Wqk[id] = f2bf(qkv_w[id] * sc);
    if (id < 512) bias_qk[id] = qkv_b[id] * ((id < 256) ? SQ : 1.0f);
  } else if (id < 196608){                // v rows (o in [512,768))
    Wv[id - 131072] = f2bf(qkv_w[id]);
  } else {                                // proj
    int j = id - 196608;
    Wp[j] = f2bf(proj_w[j]);
  }
}

// ---------------- GroupNorm + transpose: x[b][c][n] -> xn_t[b][n][c] bf16 ----------------
__global__ __launch_bounds__(256) void norm_transpose_k(const float* __restrict__ x,
                                                        const float* __restrict__ gamma,
                                                        const float* __restrict__ beta,
                                                        const float2* __restrict__ stats,
                                                        unsigned short* __restrict__ xnt){
  __shared__ float tile[64][65];
  const int b = blockIdx.z, n0 = blockIdx.x*64, c0 = blockIdx.y*64;
  const float2 st = stats[b];
  const int t = threadIdx.x;
  const int col = t & 63, rb = t >> 6;
  #pragma unroll
  for (int i = 0; i < 16; ++i){
    int rr = i*4 + rb;
    float xv = x[((size_t)b*256 + c0 + rr)*4096 + n0 + col];
    tile[rr][col] = (xv - st.x) * st.y * gamma[c0+rr] + beta[c0+rr];
  }
  __syncthreads();
  #pragma unroll
  for (int i = 0; i < 16; ++i){
    int nr = i*4 + rb;
    xnt[((size_t)b*4096 + n0 + nr)*256 + c0 + col] = f2bf(tile[col][nr]);
  }
}

// ---------------- NT GEMM: C[m][n] = sum_k A[m][k]*B[n][k], K=256 ----------------
__global__ __launch_bounds__(256) void gemm_nt_k(const unsigned short* __restrict__ A,
                                                 const unsigned short* __restrict__ B,
                                                 int lda, int ldb, long sA, long sB,
                                                 const float* __restrict__ bias_m,
                                                 const float* __restrict__ bias_n,
                                                 const float* __restrict__ resid, long sR,
                                                 float* __restrict__ outF,
                                                 unsigned short* __restrict__ outB,
                                                 int ldc, long sC){
  __shared__ unsigned short As[64][40];
  __shared__ unsigned short Bs[64][40];
  const int b  = blockIdx.z;
  const int m0 = blockIdx.x * 64, n0 = blockIdx.y * 64;
  const unsigned short* Ab = A + (size_t)b * sA;
  const unsigned short* Bb = B + (size_t)b * sB;
  const int t = threadIdx.x;
  const int lane = t & 63, w = t >> 6;
  const int g = lane >> 4, r = lane & 15;
  const int wm = (w >> 1) * 32, wn = (w & 1) * 32;
  const int lrow = t >> 2, lcol = (t & 3) * 8;
  f32x4 acc00 = {0,0,0,0}, acc01 = {0,0,0,0}, acc10 = {0,0,0,0}, acc11 = {0,0,0,0};
  for (int ks = 0; ks < 8; ++ks){
    short8 av = *(const short8*)(Ab + (size_t)(m0 + lrow) * lda + ks*32 + lcol);
    short8 bv = *(const short8*)(Bb + (size_t)(n0 + lrow) * ldb + ks*32 + lcol);
    __syncthreads();
    *(short8*)&As[lrow][lcol] = av;
    *(short8*)&Bs[lrow][lcol] = bv;
    __syncthreads();
    short8 af0 = *(const short8*)&As[wm + r][g*8];
    short8 af1 = *(const short8*)&As[wm + 16 + r][g*8];
    short8 bf0 = *(const short8*)&Bs[wn + r][g*8];
    short8 bf1 = *(const short8*)&Bs[wn + 16 + r][g*8];
    acc00 = __builtin_amdgcn_mfma_f32_16x16x32_bf16(af0, bf0, acc00, 0, 0, 0);
    acc01 = __builtin_amdgcn_mfma_f32_16x16x32_bf16(af0, bf1, acc01, 0, 0, 0);
    acc10 = __builtin_amdgcn_mfma_f32_16x16x32_bf16(af1, bf0, acc10, 0, 0, 0);
    acc11 = __builtin_amdgcn_mfma_f32_16x16x32_bf16(af1, bf1, acc11, 0, 0, 0);
  }
  f32x4 accs[2][2] = {{acc00, acc01},{acc10, acc11}};
  #pragma unroll
  for (int mi = 0; mi < 2; ++mi)
    #pragma unroll
    for (int ni = 0; ni < 2; ++ni)
      #pragma unroll
      for (int j = 0; j < 4; ++j){
        int gm = m0 + wm + mi*16 + g*4 + j;
        int gn = n0 + wn + ni*16 + r;
        float vv = accs[mi][ni][j];
        if (bias_m) vv += bias_m[gm];
        if (bias_n) vv += bias_n[gn];
        if (resid)  vv += resid[(size_t)b*sR + (size_t)gm*ldc + gn];
        size_t off = (size_t)b*sC + (size_t)gm*ldc + gn;
        if (outB) outB[off] = f2bf(vv); else outF[off] = vv;
      }
}

// ---------------- flash attention, fixed-M softmax, c-split wave pairs ----------------
// 256 blocks x 512 thr (8 waves = 4 q-subblocks x 2 c-groups). KVBLK=64, ksplit=2.
// q,k in qk[b][n][512] (q=c<256, k=c>=256), v in vbuf[b][c][n].
// p = exp2(S - 24) (no max tracking; GN-bounded scores). Partner waves exchange P via LDS.
// Writes unnormalized partial O (bf16, po[combo][c][q]) + partial l; attn_merge_k sums.
__global__ __launch_bounds__(512, 2) void attn_k(const unsigned short* __restrict__ qk,
                                                 const unsigned short* __restrict__ vbuf,
                                                 unsigned short* __restrict__ po,
                                                 float* __restrict__ ml){
  __shared__ __align__(16) char smem[147456]; // 2 x (K 32KB | V 32KB) dbuf + P 16KB
  const int id = blockIdx.x;
  const int combo = id & 7, qb = id >> 3;     // combo -> XCD; 32 q-blocks share K/V in L2
  const int b = combo >> 1, ks = combo & 1;
  const int q0 = qb * 128;
  const int t = threadIdx.x, lane = t & 63, w = t >> 6;
  const int qw = w >> 1;            // q sub-block (32 rows)
  const int cg = w & 1;             // c-group AND k-half for QK
  const int hi = lane >> 5, l31 = lane & 31;
  const unsigned short* qkb = qk + (size_t)b * 4096 * 512;
  const unsigned short* vb  = vbuf + (size_t)b * 256 * 4096;

  // ---- staging: waves 0-3 -> K (16 rows each), waves 4-7 -> V (64 c-rows each) ----
  auto stage = [&](int kt2, char* buf){
    const int kc = ks*2048 + kt2*64;
    if (w < 4){
      #pragma unroll
      for (int ii = 0; ii < 8; ++ii){
        int row = w*16 + 2*ii + hi;
        const unsigned short* src = qkb + (size_t)(kc + row)*512 + 256
                                  + (((l31*16) ^ ((row & 15) << 4)) >> 1);
        gload16(src, buf + (w*16 + 2*ii)*512);
      }
    } else {
      #pragma unroll
      for (int ii = 0; ii < 8; ++ii){
        int c = (w-4)*64 + 8*ii + (lane >> 3);
        const unsigned short* src = vb + (size_t)c*4096 + kc
                                  + ((((lane & 7)*16) ^ (((lane >> 3) & 7) << 4)) >> 1);
        gload16(src, buf + 32768 + ((w-4)*64 + 8*ii)*128);
      }
    }
  };

  // ---- Q fragments (B-operand): wave owns q-rows q0 + qw*32 + l31 ----
  short8 qf[16];
  {
    const unsigned short* qrow = qkb + (size_t)(q0 + qw*32 + l31) * 512;
    #pragma unroll
    for (int s = 0; s < 16; ++s) qf[s] = *(const short8*)(qrow + s*16 + hi*8);
  }

  f32x4 O[4][4];   // 4 c-blocks x 16 f32 (kept as 4x f32x4 rows of the f32x16 acc)
  #pragma unroll
  for (int cb = 0; cb < 4; ++cb)
    #pragma unroll
    for (int jj = 0; jj < 4; ++jj) O[cb][jj] = (f32x4){0.f,0.f,0.f,0.f};
  float lrun = 0.f;

  const int kswz = (l31 & 15) << 4;   // K rows 512B, 16-deep XOR -> conflict-free b128
  const int vswz = (l31 & 7) << 4;    // V rows 128B, 8-deep XOR  -> 4-way residual
  char* pbase = smem + 131072 + qw*4096;  // P exchange region per pair

  stage(0, smem);   // prologue

  for (int kt = 0; kt < 32; ++kt){
    char* cur = smem + (kt & 1)*65536;
    const char* Kt = cur;
    const char* Vt = cur + 32768;

    WAITV0();      // own stage of tile kt landed (issued a full iteration ago)
    BARRIER();     // (A) tile kt staged by all; prev buffer free

    if (kt < 31) stage(kt+1, smem + ((kt+1) & 1)*65536);

    // ---- S^T = K[k-half cg]·Q : 16 c-steps, 2 chains ----
    f32x16 Sa, Sb;
    #pragma unroll
    for (int jj = 0; jj < 16; ++jj){ Sa[jj] = 0.f; Sb[jj] = 0.f; }
    const char* krow = Kt + (cg*32 + l31)*512;
    __builtin_amdgcn_s_setprio(1);
    #pragma unroll
    for (int s = 0; s < 8; ++s){
      short8 k0 = *(const short8*)(krow + (((2*s  )*32 + hi*16) ^ kswz));
      short8 k1 = *(const short8*)(krow + (((2*s+1)*32 + hi*16) ^ kswz));
      Sa = __builtin_amdgcn_mfma_f32_32x32x16_bf16(k0, qf[2*s  ], Sa, 0, 0, 0);
      Sb = __builtin_amdgcn_mfma_f32_32x32x16_bf16(k1, qf[2*s+1], Sb, 0, 0, 0);
    }
    __builtin_amdgcn_s_setprio(0);

    // ---- fixed-M softmax: p = exp2(S - 24), no max tracking ----
    float p[16];
    #pragma unroll
    for (int jj = 0; jj < 16; ++jj) p[jj] = exp2f((Sa[jj] + Sb[jj]) - 24.0f);
    lrun += ((p[0]+p[1]) + (p[2]+p[3])) + ((p[4]+p[5]) + (p[6]+p[7]))
          + ((p[8]+p[9]) + (p[10]+p[11])) + ((p[12]+p[13]) + (p[14]+p[15]));

    // ---- pack P -> 2 bf16 B-fragments (k-slices of this wave's 32-k half) ----
    unsigned int w0 = cvtpk_bf16(p[0],  p[1]),  w1 = cvtpk_bf16(p[2],  p[3]);
    unsigned int w2 = cvtpk_bf16(p[4],  p[5]),  w3 = cvtpk_bf16(p[6],  p[7]);
    unsigned int w4 = cvtpk_bf16(p[8],  p[9]),  w5 = cvtpk_bf16(p[10], p[11]);
    unsigned int w6 = cvtpk_bf16(p[12], p[13]), w7 = cvtpk_bf16(p[14], p[15]);
    asm("v_permlane32_swap_b32 %0, %1" : "+v"(w0), "+v"(w2));
    asm("v_permlane32_swap_b32 %0, %1" : "+v"(w1), "+v"(w3));
    asm("v_permlane32_swap_b32 %0, %1" : "+v"(w4), "+v"(w6));
    asm("v_permlane32_swap_b32 %0, %1" : "+v"(w5), "+v"(w7));
    i32x4 pw0 = {(int)w0, (int)w1, (int)w2, (int)w3};
    i32x4 pw1 = {(int)w4, (int)w5, (int)w6, (int)w7};
    short8 pa0 = __builtin_bit_cast(short8, pw0);
    short8 pa1 = __builtin_bit_cast(short8, pw1);

    // ---- exchange P with partner wave (same qw, other cg) through LDS ----
    *(short8*)(pbase + (2*cg    )*1024 + lane*16) = pa0;
    *(short8*)(pbase + (2*cg + 1)*1024 + lane*16) = pa1;
    WAITLGKM0();
    BARRIER();     // (B) all P fragments visible
    short8 qb0 = *(const short8*)(pbase + (2*(1-cg)    )*1024 + lane*16);
    short8 qb1 = *(const short8*)(pbase + (2*(1-cg) + 1)*1024 + lane*16);
    short8 pf0 = cg ? qb0 : pa0;   // global k-slice 0 (k 0..15)
    short8 pf1 = cg ? qb1 : pa1;   // k 16..31
    short8 pf2 = cg ? pa0 : qb0;   // k 32..47
    short8 pf3 = cg ? pa1 : qb1;   // k 48..63

    // ---- O^T += V[c-half cg]·P^T : 4 c-blocks x 4 k-slices ----
    __builtin_amdgcn_s_setprio(1);
    #pragma unroll
    for (int cb = 0; cb < 4; ++cb){
      const char* vrow = Vt + (cg*128 + cb*32 + l31)*128;
      short8 vf0 = *(const short8*)(vrow + ((0*32 + hi*16) ^ vswz));
      short8 vf1 = *(const short8*)(vrow + ((1*32 + hi*16) ^ vswz));
      short8 vf2 = *(const short8*)(vrow + ((2*32 + hi*16) ^ vswz));
      short8 vf3 = *(const short8*)(vrow + ((3*32 + hi*16) ^ vswz));
      f32x16 acc;
      #pragma unroll
      for (int jj = 0; jj < 4; ++jj){
        acc[4*jj+0] = O[cb][jj][0]; acc[4*jj+1] = O[cb][jj][1];
        acc[4*jj+2] = O[cb][jj][2]; acc[4*jj+3] = O[cb][jj][3];
      }
      acc = __builtin_amdgcn_mfma_f32_32x32x16_bf16(vf0, pf0, acc, 0, 0, 0);
      acc = __builtin_amdgcn_mfma_f32_32x32x16_bf16(vf1, pf1, acc, 0, 0, 0);
      acc = __builtin_amdgcn_mfma_f32_32x32x16_bf16(vf2, pf2, acc, 0, 0, 0);
      acc = __builtin_amdgcn_mfma_f32_32x32x16_bf16(vf3, pf3, acc, 0, 0, 0);
      #pragma unroll
      for (int jj = 0; jj < 4; ++jj){
        O[cb][jj][0] = acc[4*jj+0]; O[cb][jj][1] = acc[4*jj+1];
        O[cb][jj][2] = acc[4*jj+2]; O[cb][jj][3] = acc[4*jj+3];
      }
    }
    __builtin_amdgcn_s_setprio(0);
  }

  // ---- epilogue: write unnormalized partials ----
  float lf = lrun + __shfl_xor(lrun, 32);
  const int qg = q0 + qw*32 + l31;
  unsigned short* pob = po + (size_t)combo * 1048576;   // [256 c][4096 q]
  #pragma unroll
  for (int cb = 0; cb < 4; ++cb)
    #pragma unroll
    for (int jj = 0; jj < 16; ++jj){
      int c = cg*128 + cb*32 + (jj & 3) + 8*(jj >> 2) + 4*hi;
      pob[(size_t)c*4096 + qg] = f2bf(O[cb][jj >> 2][jj & 3]);
    }
  if (lane < 32)
    ml[((size_t)combo*2 + cg)*4096 + qg] = lf;
}

// ---------------- merge the 2 k-chunks: out ho[b][q][c] bf16 ----------------
__global__ __launch_bounds__(256) void attn_merge_k(const unsigned short* __restrict__ po,
                                                    const float* __restrict__ ml,
                                                    unsigned short* __restrict__ ho){
  __shared__ float Of[64][261];
  const int b = blockIdx.y, q0 = blockIdx.x * 64;
  const int t = threadIdx.x, ql = t & 63, ci = t >> 6;
  const int q = q0 + ql;
  float L = ml[((size_t)(b*2+0)*2 + 0)*4096 + q] + ml[((size_t)(b*2+0)*2 + 1)*4096 + q]
          + ml[((size_t)(b*2+1)*2 + 0)*4096 + q] + ml[((size_t)(b*2+1)*2 + 1)*4096 + q];
  float inv = 1.0f / L;
  const unsigned short* p0 = po + (size_t)(b*2+0)*1048576 + q;
  const unsigned short* p1 = po + (size_t)(b*2+1)*1048576 + q;
  #pragma unroll
  for (int i = 0; i < 64; ++i){
    int c = ci + 4*i;
    float v = bf2f(p0[(size_t)c*4096]) + bf2f(p1[(size_t)c*4096]);
    Of[ql][c] = v * inv;
  }
  __syncthreads();
  const int qr = t >> 2, sub = t & 3;
  const float* rowp = Of[qr];
  unsigned short* dst = ho + ((size_t)(b*4096 + q0 + qr))*256;
  #pragma unroll
  for (int jj = 0; jj < 8; ++jj){
    int c = sub*8 + jj*32;
    float4 v0 = *(const float4*)(rowp + c);
    float4 v1 = *(const float4*)(rowp + c + 4);
    short8 o;
    o[0] = (short)f2bf(v0.x); o[1] = (short)f2bf(v0.y);
    o[2] = (short)f2bf(v0.z); o[3] = (short)f2bf(v0.w);
    o[4] = (short)f2bf(v1.x); o[5] = (short)f2bf(v1.y);
    o[6] = (short)f2bf(v1.z); o[7] = (short)f2bf(v1.w);
    *(short8*)(dst + c) = o;
  }
}

// ---------------- launch ----------------
extern "C" void kernel_launch(void* const* d_in, const int* in_sizes, int n_in,
                              void* d_out, int out_size, void* d_ws, size_t ws_size,
                              hipStream_t stream){
  const float* x      = (const float*)d_in[0];
  const float* gamma  = (const float*)d_in[1];
  const float* beta   = (const float*)d_in[2];
  const float* qkv_w  = (const float*)d_in[3];
  const float* qkv_b  = (const float*)d_in[4];
  const float* proj_w = (const float*)d_in[5];
  const float* proj_b = (const float*)d_in[6];
  float* out = (float*)d_out;
  char* ws = (char*)d_ws;

  float2* partial        = (float2*)(ws + 0);        // 2048 B
  float2* stats          = (float2*)(ws + 2048);     // 32 B
  float*  bias_qk        = (float*)(ws + 4096);      // 2048 B
  unsigned short* Wqk    = (unsigned short*)(ws + 8192);      // 512x256 bf16
  unsigned short* Wv     = (unsigned short*)(ws + 270336);    // 256x256
  unsigned short* Wp     = (unsigned short*)(ws + 401408);    // 256x256
  unsigned short* xnt    = (unsigned short*)(ws + 532480);    // 4x4096x256 bf16 (8.4 MB)
  unsigned short* qkbuf  = (unsigned short*)(ws + 8921088);   // 4x4096x512 bf16 (16.8 MB)
  unsigned short* vbuf   = (unsigned short*)(ws + 25698304);  // 4x256x4096 bf16 (8.4 MB)
  unsigned short* po     = (unsigned short*)(ws + 34086912);  // 8x256x4096 bf16 (16.8 MB)
  float*          ml     = (float*)(ws + 50864128);           // 8x2x4096 f32 (256 KB)
  unsigned short* ho     = xnt;  // xnt dead after QKV gemms -> reuse for attention output

  reduce_partial_k<<<dim3(64,4), 256, 0, stream>>>(x, partial);
  reduce_final_k<<<1, 256, 0, stream>>>(partial, stats);
  convert_w_k<<<1024, 256, 0, stream>>>(qkv_w, qkv_b, proj_w, Wqk, Wv, Wp, bias_qk);
  norm_transpose_k<<<dim3(64,4,4), 256, 0, stream>>>(x, gamma, beta, stats, xnt);
  // qk[b][n][o] = xn_t[b][n][:] . Wqk[o][:]   (M=4096, N=512)
  gemm_nt_k<<<dim3(64,8,4), 256, 0, stream>>>(xnt, Wqk, 256, 256, 4096L*256, 0,
      nullptr, bias_qk, nullptr, 0, nullptr, qkbuf, 512, 4096L*512);
  // v[b][o][n] = Wv[o][:] . xn_t[b][n][:]     (M=256, N=4096)
  gemm_nt_k<<<dim3(4,64,4), 256, 0, stream>>>(Wv, xnt, 256, 256, 0, 4096L*256,
      qkv_b + 512, nullptr, nullptr, 0, nullptr, vbuf, 4096, 256L*4096);
  attn_k<<<dim3(256), 512, 0, stream>>>(qkbuf, vbuf, po, ml);
  attn_merge_k<<<dim3(64,4), 256, 0, stream>>>(po, ml, ho);
  // out[b][o][n] = Wp[o][:] . ho[b][n][:] + proj_b[o] + x[b][o][n]
  gemm_nt_k<<<dim3(4,64,4), 256, 0, stream>>>(Wp, ho, 256, 256, 0, 4096L*256,
      proj_b, nullptr, x, 1048576L, out, nullptr, 4096, 1048576L);
}